// Round 4
// baseline (120.036 us; speedup 1.0000x reference)
//
#include <hip/hip_runtime.h>

#define IMG 192
#define ROWP 196   // padded LDS row stride (floats), float4-aligned

// Padded per-scale geometry:
//  scale0: O=57 PO=60  S=3  K=12  n1p=36864*60=2211840  base1=0         CV0=192*57*15
//  scale1: O=25 PO=28  S=6  K=24  n1p=36864*28=1032192  base1=11059200
//  scale2: O=9  PO=12  S=12 K=48  n1p=36864*12=442368   base1=16220160
// B1 total = 18,432,000 floats.  B2 bases {0, 3283200, 3955200}, total 4,058,880.

// ---------------------------------------------------------------------------
// Pass 1 (x-direction): LDS-staged, all 5 channels, 3 scales, padded output.
// ---------------------------------------------------------------------------
template<int O, int PO, int S, int K, int N1P>
__device__ __forceinline__ void p1_compute(const float* __restrict__ lI,
                                           const float* __restrict__ lT,
                                           float* __restrict__ B,
                                           int row, int ox, int r0) {
    const float* a = &lI[row * ROWP + ox * S];
    const float* b = &lT[row * ROWP + ox * S];
    float sI = 0.f, sT = 0.f, sI2 = 0.f, sT2 = 0.f, sIT = 0.f;
#pragma unroll
    for (int i = 0; i < K; ++i) {
        float x = a[2 * i];
        float y = b[2 * i];
        sI += x; sT += y; sI2 += x * x; sT2 += y * y; sIT += x * y;
    }
    size_t o = (size_t)(r0 + row) * PO + ox;
    B[o]                   = sI;
    B[(size_t)N1P + o]     = sT;
    B[2 * (size_t)N1P + o] = sI2;
    B[3 * (size_t)N1P + o] = sT2;
    B[4 * (size_t)N1P + o] = sIT;
}

__global__ __launch_bounds__(256) void pass1_lds(
    const float* __restrict__ I, const float* __restrict__ T,
    float* __restrict__ B1)
{
    __shared__ float lI[8 * ROWP];
    __shared__ float lT[8 * ROWP];
    const int tid = threadIdx.x;
    const int r0  = blockIdx.x * 8;                 // first row (zy index)

    const float4* I4 = (const float4*)(I + (size_t)r0 * IMG);
    const float4* T4 = (const float4*)(T + (size_t)r0 * IMG);
    float4* lI4 = (float4*)lI;
    float4* lT4 = (float4*)lT;
    for (int t = tid; t < 8 * (IMG / 4); t += 256) {   // 384 float4
        int row = t / 48, xi = t - row * 48;
        lI4[row * (ROWP / 4) + xi] = I4[t];
        lT4[row * (ROWP / 4) + xi] = T4[t];
    }
    __syncthreads();

    for (int w = tid; w < 8 * 57; w += 256) {
        int row = w / 57, ox = w - row * 57;
        p1_compute<57, 60, 3, 12, 2211840>(lI, lT, B1, row, ox, r0);
    }
    for (int w = tid; w < 8 * 25; w += 256) {
        int row = w / 25, ox = w - row * 25;
        p1_compute<25, 28, 6, 24, 1032192>(lI, lT, B1 + 11059200, row, ox, r0);
    }
    for (int w = tid; w < 8 * 9; w += 256) {
        int row = w / 9, ox = w - row * 9;
        p1_compute<9, 12, 12, 48, 442368>(lI, lT, B1 + 16220160, row, ox, r0);
    }
}

// ---------------------------------------------------------------------------
// Pass 2 (y-direction), float4-vectorized, one launch via block ranges.
// B2 layout per scale: [ch][z][oy][PO/4] float4 — write index == idx.
// ---------------------------------------------------------------------------
template<int O, int PO, int S, int K, int N1P>
__device__ __forceinline__ void passYv(const float* __restrict__ B1,
                                       float4* __restrict__ B2, int idx) {
    constexpr int POV = PO / 4;
    constexpr int CV  = IMG * O * POV;
    if (idx >= 5 * CV) return;
    int c   = idx / CV;
    int r   = idx - c * CV;
    int ox4 = r % POV;
    int t   = r / POV;
    int oy  = t % O;
    int z   = t / O;
    const float4* p = (const float4*)(B1 + (size_t)c * N1P
                       + ((size_t)z * IMG + (size_t)oy * S) * PO) + ox4;
    float4 acc = make_float4(0.f, 0.f, 0.f, 0.f);
#pragma unroll
    for (int j = 0; j < K; ++j) {
        float4 v = p[(size_t)j * 2 * POV];
        acc.x += v.x; acc.y += v.y; acc.z += v.z; acc.w += v.w;
    }
    B2[idx] = acc;
}

__global__ __launch_bounds__(256) void passY_all(
    const float* __restrict__ B1, float* __restrict__ B2)
{
    const int b = blockIdx.x;
    if (b < 3207)
        passYv<57, 60, 3, 12, 2211840>(B1, (float4*)B2,
                                       b * 256 + threadIdx.x);
    else if (b < 3864)
        passYv<25, 28, 6, 24, 1032192>(B1 + 11059200, (float4*)(B2 + 3283200),
                                       (b - 3207) * 256 + threadIdx.x);
    else
        passYv<9, 12, 12, 48, 442368>(B1 + 16220160, (float4*)(B2 + 3955200),
                                      (b - 3864) * 256 + threadIdx.x);
}

// ---------------------------------------------------------------------------
// Pass 3 (z-direction) + LNCC + weighted partial reduce, float4-vectorized.
// ---------------------------------------------------------------------------
__device__ __forceinline__ float lncc1(float i_s, float t_s, float i2, float t2,
                                       float it, float inv_numel) {
    float cross = it - i_s * t_s * inv_numel;
    float iv    = i2 - i_s * i_s * inv_numel;
    float tv    = t2 - t_s * t_s * inv_numel;
    return cross * cross / (iv * tv + 1e-5f);
}

template<int O, int PO, int S, int K>
__device__ __forceinline__ float passZv(const float* __restrict__ B2,
                                        int rv, float inv_numel, float wdiv) {
    constexpr int POV = PO / 4;
    constexpr int CV  = IMG * O * POV;
    int ox4 = rv % POV;
    int t   = rv / POV;
    int oy  = t % O;
    int oz  = t / O;
    const float4* p = (const float4*)(B2)
                      + (size_t)(oz * S) * O * POV + (size_t)oy * POV + ox4;
    float4 s0 = make_float4(0,0,0,0), s1 = s0, s2 = s0, s3 = s0, s4 = s0;
#pragma unroll
    for (int l = 0; l < K; ++l) {
        size_t off = (size_t)l * 2 * O * POV;
        float4 v0 = p[off];
        float4 v1 = p[(size_t)1 * CV + off];
        float4 v2 = p[(size_t)2 * CV + off];
        float4 v3 = p[(size_t)3 * CV + off];
        float4 v4 = p[(size_t)4 * CV + off];
        s0.x += v0.x; s0.y += v0.y; s0.z += v0.z; s0.w += v0.w;
        s1.x += v1.x; s1.y += v1.y; s1.z += v1.z; s1.w += v1.w;
        s2.x += v2.x; s2.y += v2.y; s2.z += v2.z; s2.w += v2.w;
        s3.x += v3.x; s3.y += v3.y; s3.z += v3.z; s3.w += v3.w;
        s4.x += v4.x; s4.y += v4.y; s4.z += v4.z; s4.w += v4.w;
    }
    int ox = ox4 * 4;
    float local = 0.f;
    if (ox + 0 < O) local += lncc1(s0.x, s1.x, s2.x, s3.x, s4.x, inv_numel);
    if (ox + 1 < O) local += lncc1(s0.y, s1.y, s2.y, s3.y, s4.y, inv_numel);
    if (ox + 2 < O) local += lncc1(s0.z, s1.z, s2.z, s3.z, s4.z, inv_numel);
    if (ox + 3 < O) local += lncc1(s0.w, s1.w, s2.w, s3.w, s4.w, inv_numel);
    return local * wdiv;
}

__global__ __launch_bounds__(256) void passZ_red(
    const float* __restrict__ B2, float* __restrict__ partials)
{
    const int b = blockIdx.x;
    float v = 0.f;
    if (b < 191) {                                  // 57*57*15 = 48735 vecs
        int r = b * 256 + threadIdx.x;
        if (r < 48735)
            v = passZv<57, 60, 3, 12>(B2, r, 1.f / 1728.f, 0.1f / 185193.f);
    } else if (b < 209) {                           // 25*25*7 = 4375 vecs
        int r = (b - 191) * 256 + threadIdx.x;
        if (r < 4375)
            v = passZv<25, 28, 6, 24>(B2 + 3283200, r, 1.f / 13824.f,
                                      0.3f / 15625.f);
    } else {                                        // 9*9*3 = 243 vecs
        int r = (b - 209) * 256 + threadIdx.x;
        if (r < 243)
            v = passZv<9, 12, 12, 48>(B2 + 3955200, r, 1.f / 110592.f,
                                      0.6f / 729.f);
    }
    __shared__ float red[256];
    red[threadIdx.x] = v;
    __syncthreads();
    for (int o = 128; o > 0; o >>= 1) {
        if (threadIdx.x < o) red[threadIdx.x] += red[threadIdx.x + o];
        __syncthreads();
    }
    if (threadIdx.x == 0) partials[blockIdx.x] = red[0];
}

__global__ __launch_bounds__(256) void finalize_n(
    const float* __restrict__ partials, int n, float* __restrict__ out)
{
    float v = 0.f;
    for (int i = threadIdx.x; i < n; i += 256) v += partials[i];
    __shared__ float red[256];
    red[threadIdx.x] = v;
    __syncthreads();
    for (int o = 128; o > 0; o >>= 1) {
        if (threadIdx.x < o) red[threadIdx.x] += red[threadIdx.x + o];
        __syncthreads();
    }
    if (threadIdx.x == 0) out[0] = 1.0f - red[0];
}

// ------------------- fallback kernels (small-ws path) ----------------------
__global__ void pass1_one(const float* __restrict__ I, const float* __restrict__ T,
                          float* __restrict__ B1, int O, int s, int k, int c) {
    int idx = blockIdx.x * blockDim.x + threadIdx.x;
    if (idx >= IMG * IMG * O) return;
    int ox = idx % O;
    int zy = idx / O;
    const float* pI = I + (size_t)zy * IMG + ox * s;
    const float* pT = T + (size_t)zy * IMG + ox * s;
    float acc = 0.f;
    for (int i = 0; i < k; ++i) {
        float v;
        if (c == 0)      v = pI[2 * i];
        else if (c == 1) v = pT[2 * i];
        else if (c == 2) { float a = pI[2 * i]; v = a * a; }
        else if (c == 3) { float bb = pT[2 * i]; v = bb * bb; }
        else             { v = pI[2 * i] * pT[2 * i]; }
        acc += v;
    }
    B1[idx] = acc;
}

__global__ void pass_y(const float* __restrict__ Bin, float* __restrict__ Bout,
                       int O, int s, int k, int n1, int n2) {
    int idx = blockIdx.x * blockDim.x + threadIdx.x;
    if (idx >= n2) return;
    int ox = idx % O;
    int t  = idx / O;
    int oy = t % O;
    int z  = t / O;
    const float* p = Bin + (size_t)z * IMG * O + (size_t)(oy * s) * O + ox;
    float acc = 0.f;
    for (int j = 0; j < k; ++j) acc += p[(size_t)j * 2 * O];
    Bout[idx] = acc;
}

__global__ void pass_z(const float* __restrict__ Bin, float* __restrict__ Bout,
                       int O, int s, int k, int n2, int n3) {
    int idx = blockIdx.x * blockDim.x + threadIdx.x;
    if (idx >= n3) return;
    int ox = idx % O;
    int t  = idx / O;
    int oy = t % O;
    int oz = t / O;
    const float* p = Bin + (size_t)(oz * s) * O * O + (size_t)oy * O + ox;
    float acc = 0.f;
    for (int l = 0; l < k; ++l) acc += p[(size_t)l * 2 * O * O];
    Bout[idx] = acc;
}

__global__ void reduce_one(const float* __restrict__ B3, int n3, float inv_numel,
                           float wdiv, float* __restrict__ partials) {
    float local = 0.f;
    for (int i = blockIdx.x * 256 + threadIdx.x; i < n3; i += gridDim.x * 256) {
        float i_s = B3[i];
        float t_s = B3[(size_t)n3 + i];
        float i2  = B3[2 * (size_t)n3 + i];
        float t2  = B3[3 * (size_t)n3 + i];
        float it  = B3[4 * (size_t)n3 + i];
        local += wdiv * lncc1(i_s, t_s, i2, t2, it, inv_numel);
    }
    __shared__ float red[256];
    red[threadIdx.x] = local;
    __syncthreads();
    for (int o = 128; o > 0; o >>= 1) {
        if (threadIdx.x < o) red[threadIdx.x] += red[threadIdx.x + o];
        __syncthreads();
    }
    if (threadIdx.x == 0) partials[blockIdx.x] += red[0];   // accumulate scales
}

__global__ void zero_buf(float* __restrict__ p, int n) {
    int i = blockIdx.x * 256 + threadIdx.x;
    if (i < n) p[i] = 0.f;
}

// ---------------------------------------------------------------------------
extern "C" void kernel_launch(void* const* d_in, const int* in_sizes, int n_in,
                              void* d_out, int out_size, void* d_ws, size_t ws_size,
                              hipStream_t stream) {
    const float* I = (const float*)d_in[0];
    const float* T = (const float*)d_in[1];
    float* out = (float*)d_out;
    float* ws  = (float*)d_ws;

    const size_t szB1p = 18432000;   // padded B1 floats
    const size_t szB2p = 4058880;    // padded B2 floats
    const size_t need  = (szB1p + szB2p + 1024) * sizeof(float);   // ~90 MB

    if (ws_size >= need) {
        float* B1 = ws;
        float* B2 = B1 + szB1p;
        float* partials = B2 + szB2p;
        pass1_lds<<<4608, 256, 0, stream>>>(I, T, B1);
        passY_all<<<3966, 256, 0, stream>>>(B1, B2);
        passZ_red<<<210, 256, 0, stream>>>(B2, partials);
        finalize_n<<<1, 256, 0, stream>>>(partials, 210, out);
    } else {
        // minimal-ws path: per scale, per channel pipelines (scalar, unpadded)
        const int   Ks[3] = {12, 24, 48};
        const int   Ss[3] = {3, 6, 12};
        const int   Os[3] = {57, 25, 9};
        const int   N1[3] = {2101248, 921600, 331776};
        const int   N2[3] = {623808, 120000, 15552};
        const int   N3[3] = {185193, 15625, 729};
        const float Wt[3] = {0.1f, 0.3f, 0.6f};

        float* B1 = ws;                 // n1_max = 2101248
        float* B2 = B1 + 2101248;       // n2_max = 623808
        float* B3 = B2 + 623808;        // 5 * n3_max = 925965
        float* partials = B3 + 925965;  // 256

        zero_buf<<<1, 256, 0, stream>>>(partials, 256);
        for (int sc = 0; sc < 3; ++sc) {
            int k = Ks[sc], s = Ss[sc], O = Os[sc];
            int n1 = N1[sc], n2 = N2[sc], n3 = N3[sc];
            for (int c = 0; c < 5; ++c) {
                pass1_one<<<(n1 + 255) / 256, 256, 0, stream>>>(I, T, B1, O, s, k, c);
                pass_y<<<(n2 + 255) / 256, 256, 0, stream>>>(B1, B2, O, s, k, n1, n2);
                pass_z<<<(n3 + 255) / 256, 256, 0, stream>>>(B2, B3 + (size_t)c * n3, O, s, k, n2, n3);
            }
            int nblk = (n3 + 255) / 256; if (nblk > 256) nblk = 256;
            reduce_one<<<nblk, 256, 0, stream>>>(B3, n3, 1.f / ((float)k * k * k),
                                                 Wt[sc] / (float)n3, partials);
        }
        finalize_n<<<1, 256, 0, stream>>>(partials, 256, out);
    }
}

// Round 5
// 71.959 us; speedup vs baseline: 1.6681x; 1.6681x over previous
//
#include <hip/hip_runtime.h>

#define IMG 192
#define ROWP 196   // padded LDS row stride (floats), float4-aligned

// Padded per-scale geometry:
//  scale0: O=57 PO=60  S=3  K=12  n1p=2211840  base1=0         base2=0        n3v=48735
//  scale1: O=25 PO=28  S=6  K=24  n1p=1032192  base1=11059200  base2=3283200  n3v=4375
//  scale2: O=9  PO=12  S=12 K=48  n1p=442368   base1=16220160  base2=3955200  n3v=243
// B1 = 18,432,000 fl; B2 = 4,058,880 fl; B3 bases(fl) {0, 974700, 1062200}, tot 1,067,060.

// ---------------------------------------------------------------------------
// Pass 1 (x-direction): LDS-staged, all 5 channels, 3 scales, padded output.
// ---------------------------------------------------------------------------
template<int O, int PO, int S, int K, int N1P>
__device__ __forceinline__ void p1_compute(const float* __restrict__ lI,
                                           const float* __restrict__ lT,
                                           float* __restrict__ B,
                                           int row, int ox, int r0) {
    const float* a = &lI[row * ROWP + ox * S];
    const float* b = &lT[row * ROWP + ox * S];
    float sI = 0.f, sT = 0.f, sI2 = 0.f, sT2 = 0.f, sIT = 0.f;
#pragma unroll
    for (int i = 0; i < K; ++i) {
        float x = a[2 * i];
        float y = b[2 * i];
        sI += x; sT += y; sI2 += x * x; sT2 += y * y; sIT += x * y;
    }
    size_t o = (size_t)(r0 + row) * PO + ox;
    B[o]                   = sI;
    B[(size_t)N1P + o]     = sT;
    B[2 * (size_t)N1P + o] = sI2;
    B[3 * (size_t)N1P + o] = sT2;
    B[4 * (size_t)N1P + o] = sIT;
}

__global__ __launch_bounds__(256) void pass1_lds(
    const float* __restrict__ I, const float* __restrict__ T,
    float* __restrict__ B1)
{
    __shared__ float lI[8 * ROWP];
    __shared__ float lT[8 * ROWP];
    const int tid = threadIdx.x;
    const int r0  = blockIdx.x * 8;                 // first row (zy index)

    const float4* I4 = (const float4*)(I + (size_t)r0 * IMG);
    const float4* T4 = (const float4*)(T + (size_t)r0 * IMG);
    float4* lI4 = (float4*)lI;
    float4* lT4 = (float4*)lT;
    for (int t = tid; t < 8 * (IMG / 4); t += 256) {   // 384 float4
        int row = t / 48, xi = t - row * 48;
        lI4[row * (ROWP / 4) + xi] = I4[t];
        lT4[row * (ROWP / 4) + xi] = T4[t];
    }
    __syncthreads();

    for (int w = tid; w < 8 * 57; w += 256) {
        int row = w / 57, ox = w - row * 57;
        p1_compute<57, 60, 3, 12, 2211840>(lI, lT, B1, row, ox, r0);
    }
    for (int w = tid; w < 8 * 25; w += 256) {
        int row = w / 25, ox = w - row * 25;
        p1_compute<25, 28, 6, 24, 1032192>(lI, lT, B1 + 11059200, row, ox, r0);
    }
    for (int w = tid; w < 8 * 9; w += 256) {
        int row = w / 9, ox = w - row * 9;
        p1_compute<9, 12, 12, 48, 442368>(lI, lT, B1 + 16220160, row, ox, r0);
    }
}

// ---------------------------------------------------------------------------
// Pass 2 (y-direction), float4-vectorized, one launch via block ranges.
// B2 layout per scale: [ch][z][oy][PO/4] float4 — write index == idx.
// ---------------------------------------------------------------------------
template<int O, int PO, int S, int K, int N1P>
__device__ __forceinline__ void passYv(const float* __restrict__ B1,
                                       float4* __restrict__ B2, int idx) {
    constexpr int POV = PO / 4;
    constexpr int CV  = IMG * O * POV;
    if (idx >= 5 * CV) return;
    int c   = idx / CV;
    int r   = idx - c * CV;
    int ox4 = r % POV;
    int t   = r / POV;
    int oy  = t % O;
    int z   = t / O;
    const float4* p = (const float4*)(B1 + (size_t)c * N1P
                       + ((size_t)z * IMG + (size_t)oy * S) * PO) + ox4;
    float4 acc = make_float4(0.f, 0.f, 0.f, 0.f);
#pragma unroll 8
    for (int j = 0; j < K; ++j) {
        float4 v = p[(size_t)j * 2 * POV];
        acc.x += v.x; acc.y += v.y; acc.z += v.z; acc.w += v.w;
    }
    B2[idx] = acc;
}

__global__ __launch_bounds__(256) void passY_all(
    const float* __restrict__ B1, float* __restrict__ B2)
{
    const int b = blockIdx.x;
    if (b < 3207)
        passYv<57, 60, 3, 12, 2211840>(B1, (float4*)B2,
                                       b * 256 + threadIdx.x);
    else if (b < 3864)
        passYv<25, 28, 6, 24, 1032192>(B1 + 11059200, (float4*)(B2 + 3283200),
                                       (b - 3207) * 256 + threadIdx.x);
    else
        passYv<9, 12, 12, 48, 442368>(B1 + 16220160, (float4*)(B2 + 3955200),
                                      (b - 3864) * 256 + threadIdx.x);
}

// ---------------------------------------------------------------------------
// Pass 3 (z-direction): per-channel, single float4 accumulator, low VGPR.
// B3 layout per scale: [ch][n3v] float4.
// ---------------------------------------------------------------------------
template<int O, int PO, int S, int K>
__device__ __forceinline__ void passZc(const float* __restrict__ B2,
                                       float4* __restrict__ B3, int idx) {
    constexpr int POV = PO / 4;
    constexpr int CV  = IMG * O * POV;
    constexpr int N3V = O * O * POV;
    if (idx >= 5 * N3V) return;
    int c   = idx / N3V;
    int rv  = idx - c * N3V;
    int ox4 = rv % POV;
    int t   = rv / POV;
    int oy  = t % O;
    int oz  = t / O;
    const float4* p = (const float4*)B2 + (size_t)c * CV
                      + (size_t)(oz * S) * O * POV + (size_t)oy * POV + ox4;
    float4 acc = make_float4(0.f, 0.f, 0.f, 0.f);
#pragma unroll 8
    for (int l = 0; l < K; ++l) {
        float4 v = p[(size_t)l * 2 * O * POV];
        acc.x += v.x; acc.y += v.y; acc.z += v.z; acc.w += v.w;
    }
    B3[idx] = acc;
}

__global__ __launch_bounds__(256) void passZ_all(
    const float* __restrict__ B2, float* __restrict__ B3)
{
    const int b = blockIdx.x;
    if (b < 952)
        passZc<57, 60, 3, 12>(B2, (float4*)B3, b * 256 + threadIdx.x);
    else if (b < 1038)
        passZc<25, 28, 6, 24>(B2 + 3283200, (float4*)(B3 + 974700),
                              (b - 952) * 256 + threadIdx.x);
    else
        passZc<9, 12, 12, 48>(B2 + 3955200, (float4*)(B3 + 1062200),
                              (b - 1038) * 256 + threadIdx.x);
}

// ---------------------------------------------------------------------------
// LNCC + weighted partial reduce over padded B3.
// ---------------------------------------------------------------------------
__device__ __forceinline__ float lncc1(float i_s, float t_s, float i2, float t2,
                                       float it, float inv_numel) {
    float cross = it - i_s * t_s * inv_numel;
    float iv    = i2 - i_s * i_s * inv_numel;
    float tv    = t2 - t_s * t_s * inv_numel;
    return cross * cross / (iv * tv + 1e-5f);
}

template<int O, int PO>
__device__ __forceinline__ float red_impl(const float* __restrict__ B3,
                                          int rv, float inv_numel, float wdiv) {
    constexpr int POV = PO / 4;
    constexpr int N3V = O * O * POV;
    const float4* p = (const float4*)B3;
    float4 s0 = p[rv];
    float4 s1 = p[(size_t)1 * N3V + rv];
    float4 s2 = p[(size_t)2 * N3V + rv];
    float4 s3 = p[(size_t)3 * N3V + rv];
    float4 s4 = p[(size_t)4 * N3V + rv];
    int ox = (rv % POV) * 4;
    float local = 0.f;
    if (ox + 0 < O) local += lncc1(s0.x, s1.x, s2.x, s3.x, s4.x, inv_numel);
    if (ox + 1 < O) local += lncc1(s0.y, s1.y, s2.y, s3.y, s4.y, inv_numel);
    if (ox + 2 < O) local += lncc1(s0.z, s1.z, s2.z, s3.z, s4.z, inv_numel);
    if (ox + 3 < O) local += lncc1(s0.w, s1.w, s2.w, s3.w, s4.w, inv_numel);
    return local * wdiv;
}

__global__ __launch_bounds__(256) void reduce_all(
    const float* __restrict__ B3, float* __restrict__ partials)
{
    const int b = blockIdx.x;
    float v = 0.f;
    if (b < 191) {
        int r = b * 256 + threadIdx.x;
        if (r < 48735)
            v = red_impl<57, 60>(B3, r, 1.f / 1728.f, 0.1f / 185193.f);
    } else if (b < 209) {
        int r = (b - 191) * 256 + threadIdx.x;
        if (r < 4375)
            v = red_impl<25, 28>(B3 + 974700, r, 1.f / 13824.f, 0.3f / 15625.f);
    } else {
        int r = (b - 209) * 256 + threadIdx.x;
        if (r < 243)
            v = red_impl<9, 12>(B3 + 1062200, r, 1.f / 110592.f, 0.6f / 729.f);
    }
    __shared__ float red[256];
    red[threadIdx.x] = v;
    __syncthreads();
    for (int o = 128; o > 0; o >>= 1) {
        if (threadIdx.x < o) red[threadIdx.x] += red[threadIdx.x + o];
        __syncthreads();
    }
    if (threadIdx.x == 0) partials[blockIdx.x] = red[0];
}

__global__ __launch_bounds__(256) void finalize_n(
    const float* __restrict__ partials, int n, float* __restrict__ out)
{
    float v = 0.f;
    for (int i = threadIdx.x; i < n; i += 256) v += partials[i];
    __shared__ float red[256];
    red[threadIdx.x] = v;
    __syncthreads();
    for (int o = 128; o > 0; o >>= 1) {
        if (threadIdx.x < o) red[threadIdx.x] += red[threadIdx.x + o];
        __syncthreads();
    }
    if (threadIdx.x == 0) out[0] = 1.0f - red[0];
}

// ------------------- fallback kernels (small-ws path) ----------------------
__global__ void pass1_one(const float* __restrict__ I, const float* __restrict__ T,
                          float* __restrict__ B1, int O, int s, int k, int c) {
    int idx = blockIdx.x * blockDim.x + threadIdx.x;
    if (idx >= IMG * IMG * O) return;
    int ox = idx % O;
    int zy = idx / O;
    const float* pI = I + (size_t)zy * IMG + ox * s;
    const float* pT = T + (size_t)zy * IMG + ox * s;
    float acc = 0.f;
    for (int i = 0; i < k; ++i) {
        float v;
        if (c == 0)      v = pI[2 * i];
        else if (c == 1) v = pT[2 * i];
        else if (c == 2) { float a = pI[2 * i]; v = a * a; }
        else if (c == 3) { float bb = pT[2 * i]; v = bb * bb; }
        else             { v = pI[2 * i] * pT[2 * i]; }
        acc += v;
    }
    B1[idx] = acc;
}

__global__ void pass_y(const float* __restrict__ Bin, float* __restrict__ Bout,
                       int O, int s, int k, int n1, int n2) {
    int idx = blockIdx.x * blockDim.x + threadIdx.x;
    if (idx >= n2) return;
    int ox = idx % O;
    int t  = idx / O;
    int oy = t % O;
    int z  = t / O;
    const float* p = Bin + (size_t)z * IMG * O + (size_t)(oy * s) * O + ox;
    float acc = 0.f;
    for (int j = 0; j < k; ++j) acc += p[(size_t)j * 2 * O];
    Bout[idx] = acc;
}

__global__ void pass_z(const float* __restrict__ Bin, float* __restrict__ Bout,
                       int O, int s, int k, int n2, int n3) {
    int idx = blockIdx.x * blockDim.x + threadIdx.x;
    if (idx >= n3) return;
    int ox = idx % O;
    int t  = idx / O;
    int oy = t % O;
    int oz = t / O;
    const float* p = Bin + (size_t)(oz * s) * O * O + (size_t)oy * O + ox;
    float acc = 0.f;
    for (int l = 0; l < k; ++l) acc += p[(size_t)l * 2 * O * O];
    Bout[idx] = acc;
}

__global__ void reduce_one(const float* __restrict__ B3, int n3, float inv_numel,
                           float wdiv, float* __restrict__ partials) {
    float local = 0.f;
    for (int i = blockIdx.x * 256 + threadIdx.x; i < n3; i += gridDim.x * 256) {
        float i_s = B3[i];
        float t_s = B3[(size_t)n3 + i];
        float i2  = B3[2 * (size_t)n3 + i];
        float t2  = B3[3 * (size_t)n3 + i];
        float it  = B3[4 * (size_t)n3 + i];
        local += wdiv * lncc1(i_s, t_s, i2, t2, it, inv_numel);
    }
    __shared__ float red[256];
    red[threadIdx.x] = local;
    __syncthreads();
    for (int o = 128; o > 0; o >>= 1) {
        if (threadIdx.x < o) red[threadIdx.x] += red[threadIdx.x + o];
        __syncthreads();
    }
    if (threadIdx.x == 0) partials[blockIdx.x] += red[0];   // accumulate scales
}

__global__ void zero_buf(float* __restrict__ p, int n) {
    int i = blockIdx.x * 256 + threadIdx.x;
    if (i < n) p[i] = 0.f;
}

// ---------------------------------------------------------------------------
extern "C" void kernel_launch(void* const* d_in, const int* in_sizes, int n_in,
                              void* d_out, int out_size, void* d_ws, size_t ws_size,
                              hipStream_t stream) {
    const float* I = (const float*)d_in[0];
    const float* T = (const float*)d_in[1];
    float* out = (float*)d_out;
    float* ws  = (float*)d_ws;

    const size_t szB1p = 18432000;   // padded B1 floats
    const size_t szB2p = 4058880;    // padded B2 floats
    const size_t szB3p = 1067060;    // padded B3 floats
    const size_t need  = (szB1p + szB2p + szB3p + 1024) * sizeof(float);  // ~94 MB

    if (ws_size >= need) {
        float* B1 = ws;
        float* B2 = B1 + szB1p;
        float* B3 = B2 + szB2p;
        float* partials = B3 + szB3p;
        pass1_lds<<<4608, 256, 0, stream>>>(I, T, B1);
        passY_all<<<3966, 256, 0, stream>>>(B1, B2);
        passZ_all<<<1043, 256, 0, stream>>>(B2, B3);
        reduce_all<<<210, 256, 0, stream>>>(B3, partials);
        finalize_n<<<1, 256, 0, stream>>>(partials, 210, out);
    } else {
        // minimal-ws path: per scale, per channel pipelines (scalar, unpadded)
        const int   Ks[3] = {12, 24, 48};
        const int   Ss[3] = {3, 6, 12};
        const int   Os[3] = {57, 25, 9};
        const int   N1[3] = {2101248, 921600, 331776};
        const int   N2[3] = {623808, 120000, 15552};
        const int   N3[3] = {185193, 15625, 729};
        const float Wt[3] = {0.1f, 0.3f, 0.6f};

        float* B1 = ws;                 // n1_max = 2101248
        float* B2 = B1 + 2101248;       // n2_max = 623808
        float* B3 = B2 + 623808;        // 5 * n3_max = 925965
        float* partials = B3 + 925965;  // 256

        zero_buf<<<1, 256, 0, stream>>>(partials, 256);
        for (int sc = 0; sc < 3; ++sc) {
            int k = Ks[sc], s = Ss[sc], O = Os[sc];
            int n1 = N1[sc], n2 = N2[sc], n3 = N3[sc];
            for (int c = 0; c < 5; ++c) {
                pass1_one<<<(n1 + 255) / 256, 256, 0, stream>>>(I, T, B1, O, s, k, c);
                pass_y<<<(n2 + 255) / 256, 256, 0, stream>>>(B1, B2, O, s, k, n1, n2);
                pass_z<<<(n3 + 255) / 256, 256, 0, stream>>>(B2, B3 + (size_t)c * n3, O, s, k, n2, n3);
            }
            int nblk = (n3 + 255) / 256; if (nblk > 256) nblk = 256;
            reduce_one<<<nblk, 256, 0, stream>>>(B3, n3, 1.f / ((float)k * k * k),
                                                 Wt[sc] / (float)n3, partials);
        }
        finalize_n<<<1, 256, 0, stream>>>(partials, 256, out);
    }
}